// Round 1
// baseline (9327.660 us; speedup 1.0000x reference)
//
#include <hip/hip_runtime.h>
#include <math.h>

// GNN_2_Model: fused-embed -> GAT1 -> GAT2(+res) -> gid head & edge head.
// Round 0: fp32 correctness baseline. All buffers in d_ws:
//   featA [N,512] | h1 [N,512] | h2 [N,512] | el [N,4] | er [N,4] | denom [N,4] | ee [E,4]
//   g_tmp [N,256] reuses featA; e_tmp [P,256] reuses featA+N*256 (spills into dead h1).

__device__ __forceinline__ float warp_sum(float v) {
#pragma unroll
  for (int o = 32; o > 0; o >>= 1) v += __shfl_xor(v, o);
  return v;
}

// ---------------- GEMM: C[M,Ncols] = A'[M,K] @ B[K,Ncols] ----------------
// MODE 0: A' = A (row-major M x K)
// MODE 1: A' = fused embedding: [cell_h + pos_emb[row_pos] + pos_emb[col_pos] || mf_emb[min(row_mf,5)] + mf_emb[min(col_mf,5)]], K=832
// MODE 2: A' row p = concat(A[pairs[2p]], A[pairs[2p+1]]) each 512 wide, K=1024
// BNRELU: y = relu((x + bias - mean) * rsqrt(var+1e-5) * gamma + beta)
template <int MODE, bool BNRELU>
__global__ __launch_bounds__(256) void gemm_kernel(
    const float* __restrict__ A, const float* __restrict__ B, float* __restrict__ C,
    int M, int K, int Ncols,
    const float* __restrict__ cell_h, const float* __restrict__ pos_emb,
    const float* __restrict__ mf_emb,
    const int* __restrict__ row_pos, const int* __restrict__ col_pos,
    const int* __restrict__ row_mf, const int* __restrict__ col_mf,
    const int* __restrict__ pairs,
    const float* __restrict__ bias, const float* __restrict__ gamma,
    const float* __restrict__ beta, const float* __restrict__ mean,
    const float* __restrict__ var)
{
  __shared__ float As[32][68];  // [k][m], stride 68 floats = 272B (16B-aligned rows)
  __shared__ float Bs[32][64];  // [k][n]
  const int tx = threadIdx.x, ty = threadIdx.y;
  const int tid = ty * 16 + tx;
  const int m0 = blockIdx.y * 64, n0 = blockIdx.x * 64;

  // A staging: thread -> (row = tid>>2, k-chunk of 8 at (tid&3)*8)
  const int ar = tid >> 2;
  const int akc = (tid & 3) << 3;
  const int gr = m0 + ar;
  const bool rowok = (gr < M);

  // B staging: thread -> (k = tid>>3, n-chunk of 8 at (tid&7)*8)
  const int bk = tid >> 3;
  const int bnn = (tid & 7) << 3;

  int p0 = 0, p1 = 0, rp = 0, cp = 0, rm = 0, cm = 0;
  if (MODE == 1 && rowok) {
    rp = row_pos[gr]; cp = col_pos[gr];
    rm = min(row_mf[gr], 5); cm = min(col_mf[gr], 5);
  }
  if (MODE == 2 && rowok) { p0 = pairs[2 * gr]; p1 = pairs[2 * gr + 1]; }

  float acc[4][4] = {{0.f}};

  for (int k0 = 0; k0 < K; k0 += 32) {
    float av[8];
    if (rowok) {
      const int kk = k0 + akc;
      if (MODE == 0) {
        const float4* p = (const float4*)(A + (size_t)gr * K + kk);
        *(float4*)&av[0] = p[0];
        *(float4*)&av[4] = p[1];
      } else if (MODE == 1) {
        if (kk < 768) {
          const float4* pc = (const float4*)(cell_h + (size_t)gr * 768 + kk);
          const float4* pr = (const float4*)(pos_emb + (size_t)rp * 768 + kk);
          const float4* pq = (const float4*)(pos_emb + (size_t)cp * 768 + kk);
          float4 c0 = pc[0], c1 = pc[1], r0 = pr[0], r1 = pr[1], q0 = pq[0], q1 = pq[1];
          av[0] = c0.x + r0.x + q0.x; av[1] = c0.y + r0.y + q0.y;
          av[2] = c0.z + r0.z + q0.z; av[3] = c0.w + r0.w + q0.w;
          av[4] = c1.x + r1.x + q1.x; av[5] = c1.y + r1.y + q1.y;
          av[6] = c1.z + r1.z + q1.z; av[7] = c1.w + r1.w + q1.w;
        } else {
          const int j0 = kk - 768;
          const float4* pr = (const float4*)(mf_emb + (size_t)rm * 64 + j0);
          const float4* pq = (const float4*)(mf_emb + (size_t)cm * 64 + j0);
          float4 r0 = pr[0], r1 = pr[1], q0 = pq[0], q1 = pq[1];
          av[0] = r0.x + q0.x; av[1] = r0.y + q0.y; av[2] = r0.z + q0.z; av[3] = r0.w + q0.w;
          av[4] = r1.x + q1.x; av[5] = r1.y + q1.y; av[6] = r1.z + q1.z; av[7] = r1.w + q1.w;
        }
      } else {  // MODE 2: gathered pair rows from A (= h2, [N,512])
        const int kk2 = k0 + akc;
        const float* base = (kk2 < 512) ? (A + (size_t)p0 * 512 + kk2)
                                        : (A + (size_t)p1 * 512 + (kk2 - 512));
        const float4* p = (const float4*)base;
        *(float4*)&av[0] = p[0];
        *(float4*)&av[4] = p[1];
      }
    } else {
#pragma unroll
      for (int j = 0; j < 8; j++) av[j] = 0.f;
    }
    float bv[8];
    {
      const float4* p = (const float4*)(B + (size_t)(k0 + bk) * Ncols + n0 + bnn);
      *(float4*)&bv[0] = p[0];
      *(float4*)&bv[4] = p[1];
    }
    __syncthreads();
#pragma unroll
    for (int j = 0; j < 8; j++) As[akc + j][ar] = av[j];
    *(float4*)&Bs[bk][bnn] = *(float4*)&bv[0];
    *(float4*)&Bs[bk][bnn + 4] = *(float4*)&bv[4];
    __syncthreads();
#pragma unroll
    for (int kk = 0; kk < 32; kk++) {
      float4 a4 = *(const float4*)&As[kk][ty << 2];
      float4 b4 = *(const float4*)&Bs[kk][tx << 2];
      float ax[4] = {a4.x, a4.y, a4.z, a4.w};
      float bx[4] = {b4.x, b4.y, b4.z, b4.w};
#pragma unroll
      for (int i = 0; i < 4; i++)
#pragma unroll
        for (int j = 0; j < 4; j++) acc[i][j] = fmaf(ax[i], bx[j], acc[i][j]);
    }
  }

#pragma unroll
  for (int i = 0; i < 4; i++) {
    const int row = m0 + (ty << 2) + i;
    if (row >= M) continue;
    float vals[4];
#pragma unroll
    for (int j = 0; j < 4; j++) {
      const int col = n0 + (tx << 2) + j;
      float v = acc[i][j];
      if (BNRELU) {
        const float rs = rsqrtf(var[col] + 1e-5f);
        v = (v + bias[col] - mean[col]) * rs * gamma[col] + beta[col];
        v = fmaxf(v, 0.f);
      }
      vals[j] = v;
    }
    *(float4*)(C + (size_t)row * Ncols + n0 + (tx << 2)) = *(float4*)vals;
  }
}

// el[n,h] = sum_d feat[n,h,d]*al[h,d]; er likewise. One wave per node.
__global__ __launch_bounds__(256) void elr_kernel(
    const float* __restrict__ feat, const float* __restrict__ al,
    const float* __restrict__ ar, float* __restrict__ el, float* __restrict__ er, int N)
{
  const int wv = (blockIdx.x * 256 + threadIdx.x) >> 6;
  const int lane = threadIdx.x & 63;
  if (wv >= N) return;
  const float* f = feat + (size_t)wv * 512;
#pragma unroll
  for (int h = 0; h < 4; h++) {
    const float x0 = f[h * 128 + lane];
    const float x1 = f[h * 128 + 64 + lane];
    float sl = x0 * al[h * 128 + lane] + x1 * al[h * 128 + 64 + lane];
    float sr = x0 * ar[h * 128 + lane] + x1 * ar[h * 128 + 64 + lane];
    sl = warp_sum(sl);
    sr = warp_sum(sr);
    if (lane == 0) { el[(size_t)wv * 4 + h] = sl; er[(size_t)wv * 4 + h] = sr; }
  }
}

// Per-edge: ee = exp(leaky_relu(el[src]+er[dst])); denom[dst] += ee.
// (No segment-max shift: softmax is shift-invariant; exponents bounded ~e^10 in fp32.)
__global__ __launch_bounds__(256) void epass1_kernel(
    const int* __restrict__ src, const int* __restrict__ dst,
    const float* __restrict__ el, const float* __restrict__ er,
    float* __restrict__ ee, float* __restrict__ denom, int E)
{
  const int e = blockIdx.x * 256 + threadIdx.x;
  if (e >= E) return;
  const int s = src[e], d = dst[e];
  const float4 l4 = *(const float4*)(el + (size_t)s * 4);
  const float4 r4 = *(const float4*)(er + (size_t)d * 4);
  float xs[4] = {l4.x + r4.x, l4.y + r4.y, l4.z + r4.z, l4.w + r4.w};
  float o[4];
#pragma unroll
  for (int h = 0; h < 4; h++) {
    float x = xs[h];
    x = (x > 0.f) ? x : 0.2f * x;
    o[h] = expf(x);
    unsafeAtomicAdd(denom + (size_t)d * 4 + h, o[h]);
  }
  *(float4*)(ee + (size_t)e * 4) = *(float4*)o;
}

// One wave per edge: out[dst] += feat[src] * (ee/denom[dst]) across 512 feats.
__global__ __launch_bounds__(256) void epass2_kernel(
    const int* __restrict__ src, const int* __restrict__ dst,
    const float* __restrict__ ee, const float* __restrict__ denom,
    const float* __restrict__ feat, float* __restrict__ out, int E)
{
  const int e = (blockIdx.x * 256 + threadIdx.x) >> 6;
  const int lane = threadIdx.x & 63;
  if (e >= E) return;
  const int s = src[e], d = dst[e];
  const int ha = lane >> 5;        // head of elems lane*4 .. lane*4+3 (0..255)
  const int hb = 2 + (lane >> 5);  // head of elems 256+lane*4 ..
  const float aa = ee[(size_t)e * 4 + ha] / denom[(size_t)d * 4 + ha];
  const float ab = ee[(size_t)e * 4 + hb] / denom[(size_t)d * 4 + hb];
  const float* f = feat + (size_t)s * 512;
  const float4 v0 = *(const float4*)(f + lane * 4);
  const float4 v1 = *(const float4*)(f + 256 + lane * 4);
  float* o = out + (size_t)d * 512;
  unsafeAtomicAdd(o + lane * 4 + 0, v0.x * aa);
  unsafeAtomicAdd(o + lane * 4 + 1, v0.y * aa);
  unsafeAtomicAdd(o + lane * 4 + 2, v0.z * aa);
  unsafeAtomicAdd(o + lane * 4 + 3, v0.w * aa);
  unsafeAtomicAdd(o + 256 + lane * 4 + 0, v1.x * ab);
  unsafeAtomicAdd(o + 256 + lane * 4 + 1, v1.y * ab);
  unsafeAtomicAdd(o + 256 + lane * 4 + 2, v1.z * ab);
  unsafeAtomicAdd(o + 256 + lane * 4 + 3, v1.w * ab);
}

__global__ __launch_bounds__(256) void bias_add_kernel(
    float* __restrict__ h, const float* __restrict__ b, int total4)
{
  const int i = blockIdx.x * 256 + threadIdx.x;
  if (i >= total4) return;
  float4 v = ((float4*)h)[i];
  const float4 bb = ((const float4*)b)[i & 127];
  v.x += bb.x; v.y += bb.y; v.z += bb.z; v.w += bb.w;
  ((float4*)h)[i] = v;
}

__global__ __launch_bounds__(256) void resid_bias_kernel(
    float* __restrict__ h2, const float* __restrict__ h1,
    const float* __restrict__ b, int total4)
{
  const int i = blockIdx.x * 256 + threadIdx.x;
  if (i >= total4) return;
  float4 v = ((float4*)h2)[i];
  const float4 u = ((const float4*)h1)[i];
  const float4 bb = ((const float4*)b)[i & 127];
  v.x += u.x + bb.x; v.y += u.y + bb.y; v.z += u.z + bb.z; v.w += u.w + bb.w;
  ((float4*)h2)[i] = v;
}

// gid logits: one wave per node; g_tmp[n,:256] @ Wg2[256,4] + bg2.
__global__ __launch_bounds__(256) void gid2_kernel(
    const float* __restrict__ g, const float* __restrict__ Wg2,
    const float* __restrict__ bg2, float* __restrict__ out, int N)
{
  const int wv = (blockIdx.x * 256 + threadIdx.x) >> 6;
  const int lane = threadIdx.x & 63;
  if (wv >= N) return;
  const float4 gv = *(const float4*)(g + (size_t)wv * 256 + lane * 4);
  const float ga[4] = {gv.x, gv.y, gv.z, gv.w};
  float a0 = 0.f, a1 = 0.f, a2 = 0.f, a3 = 0.f;
  const float* wp = Wg2 + (size_t)lane * 16;
#pragma unroll
  for (int j = 0; j < 4; j++) {
    const float4 w = *(const float4*)(wp + j * 4);
    a0 += ga[j] * w.x; a1 += ga[j] * w.y; a2 += ga[j] * w.z; a3 += ga[j] * w.w;
  }
  a0 = warp_sum(a0); a1 = warp_sum(a1); a2 = warp_sum(a2); a3 = warp_sum(a3);
  if (lane == 0) {
    float4 o = {a0 + bg2[0], a1 + bg2[1], a2 + bg2[2], a3 + bg2[3]};
    *(float4*)(out + (size_t)wv * 4) = o;
  }
}

// edge logits: one wave per pair; e_tmp[p,:256] @ We2[256,1] + be2.
__global__ __launch_bounds__(256) void edge2_kernel(
    const float* __restrict__ etmp, const float* __restrict__ We2,
    const float* __restrict__ be2, float* __restrict__ out, int P)
{
  const int wv = (blockIdx.x * 256 + threadIdx.x) >> 6;
  const int lane = threadIdx.x & 63;
  if (wv >= P) return;
  const float4 v = *(const float4*)(etmp + (size_t)wv * 256 + lane * 4);
  const float4 w = *(const float4*)(We2 + (size_t)lane * 4);
  float s = v.x * w.x + v.y * w.y + v.z * w.z + v.w * w.w;
  s = warp_sum(s);
  if (lane == 0) out[wv] = s + be2[0];
}

extern "C" void kernel_launch(void* const* d_in, const int* in_sizes, int n_in,
                              void* d_out, int out_size, void* d_ws, size_t ws_size,
                              hipStream_t stream) {
  const float* cell_h  = (const float*)d_in[0];
  const float* pos_emb = (const float*)d_in[1];
  const float* mf_emb  = (const float*)d_in[2];
  const float* W1  = (const float*)d_in[3];
  const float* al1 = (const float*)d_in[4];
  const float* ar1 = (const float*)d_in[5];
  const float* b1  = (const float*)d_in[6];
  const float* W2  = (const float*)d_in[7];
  const float* al2 = (const float*)d_in[8];
  const float* ar2 = (const float*)d_in[9];
  const float* b2  = (const float*)d_in[10];
  const float* Wg1 = (const float*)d_in[11];
  const float* bg1 = (const float*)d_in[12];
  const float* g_gamma = (const float*)d_in[13];
  const float* g_beta  = (const float*)d_in[14];
  const float* g_mean  = (const float*)d_in[15];
  const float* g_var   = (const float*)d_in[16];
  const float* Wg2 = (const float*)d_in[17];
  const float* bg2 = (const float*)d_in[18];
  const float* We1 = (const float*)d_in[19];
  const float* be1 = (const float*)d_in[20];
  const float* e_gamma = (const float*)d_in[21];
  const float* e_beta  = (const float*)d_in[22];
  const float* e_mean  = (const float*)d_in[23];
  const float* e_var   = (const float*)d_in[24];
  const float* We2 = (const float*)d_in[25];
  const float* be2 = (const float*)d_in[26];
  const int* src = (const int*)d_in[27];
  const int* dst = (const int*)d_in[28];
  const int* row_pos = (const int*)d_in[29];
  const int* col_pos = (const int*)d_in[30];
  const int* row_mf  = (const int*)d_in[31];
  const int* col_mf  = (const int*)d_in[32];
  const int* pairs   = (const int*)d_in[33];

  const int N = in_sizes[0] / 768;
  const int E = in_sizes[27];
  const int P = in_sizes[33] / 2;

  float* ws = (float*)d_ws;
  float* featA = ws;                            // [N,512] feat1, then feat2
  float* h1    = featA + (size_t)N * 512;       // [N,512]
  float* h2    = h1 + (size_t)N * 512;          // [N,512]
  float* el    = h2 + (size_t)N * 512;          // [N,4]
  float* er    = el + (size_t)N * 4;            // [N,4]
  float* denom = er + (size_t)N * 4;            // [N,4]
  float* ee    = denom + (size_t)N * 4;         // [E,4]
  float* g_tmp = featA;                         // [N,256] (featA dead by then)
  float* e_tmp = featA + (size_t)N * 256;       // [P,256] (spans dead featA/h1)

  const dim3 blk(16, 16);
  const int mtiles = (N + 63) / 64;
  const int nodeWaves = (N + 3) / 4;
  const int total4 = N * 128;  // float4 count of an [N,512] buffer

  // ---- embed + GAT layer 1 ----
  gemm_kernel<1, false><<<dim3(8, mtiles), blk, 0, stream>>>(
      nullptr, W1, featA, N, 832, 512,
      cell_h, pos_emb, mf_emb, row_pos, col_pos, row_mf, col_mf,
      nullptr, nullptr, nullptr, nullptr, nullptr, nullptr);
  elr_kernel<<<nodeWaves, 256, 0, stream>>>(featA, al1, ar1, el, er, N);
  hipMemsetAsync(denom, 0, (size_t)N * 4 * sizeof(float), stream);
  hipMemsetAsync(h1, 0, (size_t)N * 512 * sizeof(float), stream);
  epass1_kernel<<<(E + 255) / 256, 256, 0, stream>>>(src, dst, el, er, ee, denom, E);
  epass2_kernel<<<(E + 3) / 4, 256, 0, stream>>>(src, dst, ee, denom, featA, h1, E);
  bias_add_kernel<<<(total4 + 255) / 256, 256, 0, stream>>>(h1, b1, total4);

  // ---- GAT layer 2 (identity residual) ----
  gemm_kernel<0, false><<<dim3(8, mtiles), blk, 0, stream>>>(
      h1, W2, featA, N, 512, 512,
      nullptr, nullptr, nullptr, nullptr, nullptr, nullptr, nullptr,
      nullptr, nullptr, nullptr, nullptr, nullptr, nullptr);
  elr_kernel<<<nodeWaves, 256, 0, stream>>>(featA, al2, ar2, el, er, N);
  hipMemsetAsync(denom, 0, (size_t)N * 4 * sizeof(float), stream);
  hipMemsetAsync(h2, 0, (size_t)N * 512 * sizeof(float), stream);
  epass1_kernel<<<(E + 255) / 256, 256, 0, stream>>>(src, dst, el, er, ee, denom, E);
  epass2_kernel<<<(E + 3) / 4, 256, 0, stream>>>(src, dst, ee, denom, featA, h2, E);
  resid_bias_kernel<<<(total4 + 255) / 256, 256, 0, stream>>>(h2, h1, b2, total4);

  // ---- comp_and_gid head ----
  gemm_kernel<0, true><<<dim3(4, mtiles), blk, 0, stream>>>(
      h2, Wg1, g_tmp, N, 512, 256,
      nullptr, nullptr, nullptr, nullptr, nullptr, nullptr, nullptr,
      nullptr, bg1, g_gamma, g_beta, g_mean, g_var);
  gid2_kernel<<<nodeWaves, 256, 0, stream>>>(g_tmp, Wg2, bg2, (float*)d_out, N);

  // ---- edge head ----
  gemm_kernel<2, true><<<dim3(4, (P + 63) / 64), blk, 0, stream>>>(
      h2, We1, e_tmp, P, 1024, 256,
      nullptr, nullptr, nullptr, nullptr, nullptr, nullptr, nullptr,
      pairs, be1, e_gamma, e_beta, e_mean, e_var);
  edge2_kernel<<<(P + 3) / 4, 256, 0, stream>>>(
      e_tmp, We2, be2, (float*)d_out + (size_t)N * 4, P);
}

// Round 2
// 2880.156 us; speedup vs baseline: 3.2386x; 3.2386x over previous
//
#include <hip/hip_runtime.h>
#include <math.h>

// GNN_2_Model: fused-embed -> GAT1 -> GAT2(+res) -> gid head & edge head.
// Round 1: replace scatter-atomic aggregation (4GB HBM write amp) with
// CSR gather-aggregate. CSR (by dst) built once on device, reused by both layers.
// ws layout (floats): featA [N,512] | h1 [N,512] | h2 [N,512] | el [N,4] | er [N,4]
//   then ints: offsets [N+1] | counts/cursor [N] | csr_src [E]
//   g_tmp [N,256] reuses featA; e_tmp [P,256] reuses featA+N*256 (spills into dead h1).

__device__ __forceinline__ float warp_sum(float v) {
#pragma unroll
  for (int o = 32; o > 0; o >>= 1) v += __shfl_xor(v, o);
  return v;
}

// ---------------- GEMM: C[M,Ncols] = A'[M,K] @ B[K,Ncols] ----------------
// MODE 0: A' = A (row-major M x K)
// MODE 1: A' = fused embedding, K=832
// MODE 2: A' row p = concat(A[pairs[2p]], A[pairs[2p+1]]) each 512 wide, K=1024
// BNRELU: y = relu((x + bias - mean) * rsqrt(var+1e-5) * gamma + beta)
template <int MODE, bool BNRELU>
__global__ __launch_bounds__(256) void gemm_kernel(
    const float* __restrict__ A, const float* __restrict__ B, float* __restrict__ C,
    int M, int K, int Ncols,
    const float* __restrict__ cell_h, const float* __restrict__ pos_emb,
    const float* __restrict__ mf_emb,
    const int* __restrict__ row_pos, const int* __restrict__ col_pos,
    const int* __restrict__ row_mf, const int* __restrict__ col_mf,
    const int* __restrict__ pairs,
    const float* __restrict__ bias, const float* __restrict__ gamma,
    const float* __restrict__ beta, const float* __restrict__ mean,
    const float* __restrict__ var)
{
  __shared__ float As[32][68];  // [k][m]
  __shared__ float Bs[32][64];  // [k][n]
  const int tx = threadIdx.x, ty = threadIdx.y;
  const int tid = ty * 16 + tx;
  const int m0 = blockIdx.y * 64, n0 = blockIdx.x * 64;

  const int ar = tid >> 2;
  const int akc = (tid & 3) << 3;
  const int gr = m0 + ar;
  const bool rowok = (gr < M);

  const int bk = tid >> 3;
  const int bnn = (tid & 7) << 3;

  int p0 = 0, p1 = 0, rp = 0, cp = 0, rm = 0, cm = 0;
  if (MODE == 1 && rowok) {
    rp = row_pos[gr]; cp = col_pos[gr];
    rm = min(row_mf[gr], 5); cm = min(col_mf[gr], 5);
  }
  if (MODE == 2 && rowok) { p0 = pairs[2 * gr]; p1 = pairs[2 * gr + 1]; }

  float acc[4][4] = {{0.f}};

  for (int k0 = 0; k0 < K; k0 += 32) {
    float av[8];
    if (rowok) {
      const int kk = k0 + akc;
      if (MODE == 0) {
        const float4* p = (const float4*)(A + (size_t)gr * K + kk);
        *(float4*)&av[0] = p[0];
        *(float4*)&av[4] = p[1];
      } else if (MODE == 1) {
        if (kk < 768) {
          const float4* pc = (const float4*)(cell_h + (size_t)gr * 768 + kk);
          const float4* pr = (const float4*)(pos_emb + (size_t)rp * 768 + kk);
          const float4* pq = (const float4*)(pos_emb + (size_t)cp * 768 + kk);
          float4 c0 = pc[0], c1 = pc[1], r0 = pr[0], r1 = pr[1], q0 = pq[0], q1 = pq[1];
          av[0] = c0.x + r0.x + q0.x; av[1] = c0.y + r0.y + q0.y;
          av[2] = c0.z + r0.z + q0.z; av[3] = c0.w + r0.w + q0.w;
          av[4] = c1.x + r1.x + q1.x; av[5] = c1.y + r1.y + q1.y;
          av[6] = c1.z + r1.z + q1.z; av[7] = c1.w + r1.w + q1.w;
        } else {
          const int j0 = kk - 768;
          const float4* pr = (const float4*)(mf_emb + (size_t)rm * 64 + j0);
          const float4* pq = (const float4*)(mf_emb + (size_t)cm * 64 + j0);
          float4 r0 = pr[0], r1 = pr[1], q0 = pq[0], q1 = pq[1];
          av[0] = r0.x + q0.x; av[1] = r0.y + q0.y; av[2] = r0.z + q0.z; av[3] = r0.w + q0.w;
          av[4] = r1.x + q1.x; av[5] = r1.y + q1.y; av[6] = r1.z + q1.z; av[7] = r1.w + q1.w;
        }
      } else {  // MODE 2
        const int kk2 = k0 + akc;
        const float* base = (kk2 < 512) ? (A + (size_t)p0 * 512 + kk2)
                                        : (A + (size_t)p1 * 512 + (kk2 - 512));
        const float4* p = (const float4*)base;
        *(float4*)&av[0] = p[0];
        *(float4*)&av[4] = p[1];
      }
    } else {
#pragma unroll
      for (int j = 0; j < 8; j++) av[j] = 0.f;
    }
    float bv[8];
    {
      const float4* p = (const float4*)(B + (size_t)(k0 + bk) * Ncols + n0 + bnn);
      *(float4*)&bv[0] = p[0];
      *(float4*)&bv[4] = p[1];
    }
    __syncthreads();
#pragma unroll
    for (int j = 0; j < 8; j++) As[akc + j][ar] = av[j];
    *(float4*)&Bs[bk][bnn] = *(float4*)&bv[0];
    *(float4*)&Bs[bk][bnn + 4] = *(float4*)&bv[4];
    __syncthreads();
#pragma unroll
    for (int kk = 0; kk < 32; kk++) {
      float4 a4 = *(const float4*)&As[kk][ty << 2];
      float4 b4 = *(const float4*)&Bs[kk][tx << 2];
      float ax[4] = {a4.x, a4.y, a4.z, a4.w};
      float bx[4] = {b4.x, b4.y, b4.z, b4.w};
#pragma unroll
      for (int i = 0; i < 4; i++)
#pragma unroll
        for (int j = 0; j < 4; j++) acc[i][j] = fmaf(ax[i], bx[j], acc[i][j]);
    }
  }

#pragma unroll
  for (int i = 0; i < 4; i++) {
    const int row = m0 + (ty << 2) + i;
    if (row >= M) continue;
    float vals[4];
#pragma unroll
    for (int j = 0; j < 4; j++) {
      const int col = n0 + (tx << 2) + j;
      float v = acc[i][j];
      if (BNRELU) {
        const float rs = rsqrtf(var[col] + 1e-5f);
        v = (v + bias[col] - mean[col]) * rs * gamma[col] + beta[col];
        v = fmaxf(v, 0.f);
      }
      vals[j] = v;
    }
    *(float4*)(C + (size_t)row * Ncols + n0 + (tx << 2)) = *(float4*)vals;
  }
}

// el[n,h] = sum_d feat[n,h,d]*al[h,d]; er likewise. One wave per node.
__global__ __launch_bounds__(256) void elr_kernel(
    const float* __restrict__ feat, const float* __restrict__ al,
    const float* __restrict__ ar, float* __restrict__ el, float* __restrict__ er, int N)
{
  const int wv = (blockIdx.x * 256 + threadIdx.x) >> 6;
  const int lane = threadIdx.x & 63;
  if (wv >= N) return;
  const float* f = feat + (size_t)wv * 512;
#pragma unroll
  for (int h = 0; h < 4; h++) {
    const float x0 = f[h * 128 + lane];
    const float x1 = f[h * 128 + 64 + lane];
    float sl = x0 * al[h * 128 + lane] + x1 * al[h * 128 + 64 + lane];
    float sr = x0 * ar[h * 128 + lane] + x1 * ar[h * 128 + 64 + lane];
    sl = warp_sum(sl);
    sr = warp_sum(sr);
    if (lane == 0) { el[(size_t)wv * 4 + h] = sl; er[(size_t)wv * 4 + h] = sr; }
  }
}

// ---------------- CSR build (by dst), done once ----------------
__global__ __launch_bounds__(256) void hist_kernel(
    const int* __restrict__ dst, int* __restrict__ counts, int E)
{
  const int e = blockIdx.x * 256 + threadIdx.x;
  if (e < E) atomicAdd(counts + dst[e], 1);
}

__global__ __launch_bounds__(1024) void scan_kernel(
    const int* __restrict__ counts, int* __restrict__ offsets, int N)
{
  __shared__ int sums[1024];
  const int t = threadIdx.x;
  const int chunk = (N + 1023) >> 10;
  const int beg = t * chunk;
  const int end = min(beg + chunk, N);
  int s = 0;
  for (int i = beg; i < end; ++i) s += counts[i];
  sums[t] = s;
  __syncthreads();
  for (int o = 1; o < 1024; o <<= 1) {
    int u = (t >= o) ? sums[t - o] : 0;
    __syncthreads();
    sums[t] += u;
    __syncthreads();
  }
  int run = sums[t] - s;  // exclusive prefix of this thread's chunk
  for (int i = beg; i < end; ++i) { offsets[i] = run; run += counts[i]; }
  if (t == 1023) offsets[N] = sums[1023];
}

__global__ __launch_bounds__(256) void scatter_kernel(
    const int* __restrict__ src, const int* __restrict__ dst,
    const int* __restrict__ offsets, int* __restrict__ cursor,
    int* __restrict__ csr_src, int E)
{
  const int e = blockIdx.x * 256 + threadIdx.x;
  if (e >= E) return;
  const int d = dst[e];
  const int pos = offsets[d] + atomicAdd(cursor + d, 1);
  csr_src[pos] = src[e];
}

// ---------------- GAT aggregate: one wave per dst node ----------------
// out[n] = sum_{s in nbr(n)} softmax(leaky(el[s]+er[n])) * feat[s]  (+resid) + bias
template <bool RES>
__global__ __launch_bounds__(256) void gat_aggregate_kernel(
    const int* __restrict__ csr_src, const int* __restrict__ offsets,
    const float* __restrict__ el, const float* __restrict__ er,
    const float* __restrict__ feat, const float* __restrict__ bias,
    const float* __restrict__ resid, float* __restrict__ out, int N)
{
  const int node = (blockIdx.x * 256 + threadIdx.x) >> 6;
  const int lane = threadIdx.x & 63;
  if (node >= N) return;
  const int beg = offsets[node], end = offsets[node + 1];
  const float4 erd = *(const float4*)(er + (size_t)node * 4);

  // pass 1: softmax denominators (lanes parallel over incident edges)
  float d0 = 0.f, d1 = 0.f, d2 = 0.f, d3 = 0.f;
  for (int i = beg + lane; i < end; i += 64) {
    const int s = csr_src[i];
    const float4 l = *(const float4*)(el + (size_t)s * 4);
    float x0 = l.x + erd.x, x1 = l.y + erd.y, x2 = l.z + erd.z, x3 = l.w + erd.w;
    x0 = x0 > 0.f ? x0 : 0.2f * x0;
    x1 = x1 > 0.f ? x1 : 0.2f * x1;
    x2 = x2 > 0.f ? x2 : 0.2f * x2;
    x3 = x3 > 0.f ? x3 : 0.2f * x3;
    d0 += __expf(x0); d1 += __expf(x1); d2 += __expf(x2); d3 += __expf(x3);
  }
  d0 = warp_sum(d0); d1 = warp_sum(d1); d2 = warp_sum(d2); d3 = warp_sum(d3);
  const float r0 = 1.f / d0, r1 = 1.f / d1, r2 = 1.f / d2, r3 = 1.f / d3;

  // pass 2: weighted gather-accumulate. lane owns feats [lane*4, +4) and [256+lane*4, +4)
  float a00 = 0.f, a01 = 0.f, a02 = 0.f, a03 = 0.f;
  float a10 = 0.f, a11 = 0.f, a12 = 0.f, a13 = 0.f;
  for (int i = beg; i < end; ++i) {
    const int s = csr_src[i];  // uniform across wave -> broadcast
    const float4 l = *(const float4*)(el + (size_t)s * 4);
    float x0 = l.x + erd.x, x1 = l.y + erd.y, x2 = l.z + erd.z, x3 = l.w + erd.w;
    x0 = x0 > 0.f ? x0 : 0.2f * x0;
    x1 = x1 > 0.f ? x1 : 0.2f * x1;
    x2 = x2 > 0.f ? x2 : 0.2f * x2;
    x3 = x3 > 0.f ? x3 : 0.2f * x3;
    const float al0 = __expf(x0) * r0, al1 = __expf(x1) * r1;
    const float al2 = __expf(x2) * r2, al3 = __expf(x3) * r3;
    const float aa = (lane < 32) ? al0 : al1;  // head of feats [0,256)
    const float ab = (lane < 32) ? al2 : al3;  // head of feats [256,512)
    const float* f = feat + (size_t)s * 512;
    const float4 v0 = *(const float4*)(f + lane * 4);
    const float4 v1 = *(const float4*)(f + 256 + lane * 4);
    a00 = fmaf(v0.x, aa, a00); a01 = fmaf(v0.y, aa, a01);
    a02 = fmaf(v0.z, aa, a02); a03 = fmaf(v0.w, aa, a03);
    a10 = fmaf(v1.x, ab, a10); a11 = fmaf(v1.y, ab, a11);
    a12 = fmaf(v1.z, ab, a12); a13 = fmaf(v1.w, ab, a13);
  }

  // epilogue: + bias (+ residual), single coalesced store
  const float4 b0 = *(const float4*)(bias + lane * 4);
  const float4 b1 = *(const float4*)(bias + 256 + lane * 4);
  float4 o0 = {a00 + b0.x, a01 + b0.y, a02 + b0.z, a03 + b0.w};
  float4 o1 = {a10 + b1.x, a11 + b1.y, a12 + b1.z, a13 + b1.w};
  if (RES) {
    const float* rr = resid + (size_t)node * 512;
    const float4 q0 = *(const float4*)(rr + lane * 4);
    const float4 q1 = *(const float4*)(rr + 256 + lane * 4);
    o0.x += q0.x; o0.y += q0.y; o0.z += q0.z; o0.w += q0.w;
    o1.x += q1.x; o1.y += q1.y; o1.z += q1.z; o1.w += q1.w;
  }
  float* op = out + (size_t)node * 512;
  *(float4*)(op + lane * 4) = o0;
  *(float4*)(op + 256 + lane * 4) = o1;
}

// gid logits: one wave per node; g_tmp[n,:256] @ Wg2[256,4] + bg2.
__global__ __launch_bounds__(256) void gid2_kernel(
    const float* __restrict__ g, const float* __restrict__ Wg2,
    const float* __restrict__ bg2, float* __restrict__ out, int N)
{
  const int wv = (blockIdx.x * 256 + threadIdx.x) >> 6;
  const int lane = threadIdx.x & 63;
  if (wv >= N) return;
  const float4 gv = *(const float4*)(g + (size_t)wv * 256 + lane * 4);
  const float ga[4] = {gv.x, gv.y, gv.z, gv.w};
  float a0 = 0.f, a1 = 0.f, a2 = 0.f, a3 = 0.f;
  const float* wp = Wg2 + (size_t)lane * 16;
#pragma unroll
  for (int j = 0; j < 4; j++) {
    const float4 w = *(const float4*)(wp + j * 4);
    a0 += ga[j] * w.x; a1 += ga[j] * w.y; a2 += ga[j] * w.z; a3 += ga[j] * w.w;
  }
  a0 = warp_sum(a0); a1 = warp_sum(a1); a2 = warp_sum(a2); a3 = warp_sum(a3);
  if (lane == 0) {
    float4 o = {a0 + bg2[0], a1 + bg2[1], a2 + bg2[2], a3 + bg2[3]};
    *(float4*)(out + (size_t)wv * 4) = o;
  }
}

// edge logits: one wave per pair; e_tmp[p,:256] @ We2[256,1] + be2.
__global__ __launch_bounds__(256) void edge2_kernel(
    const float* __restrict__ etmp, const float* __restrict__ We2,
    const float* __restrict__ be2, float* __restrict__ out, int P)
{
  const int wv = (blockIdx.x * 256 + threadIdx.x) >> 6;
  const int lane = threadIdx.x & 63;
  if (wv >= P) return;
  const float4 v = *(const float4*)(etmp + (size_t)wv * 256 + lane * 4);
  const float4 w = *(const float4*)(We2 + (size_t)lane * 4);
  float s = v.x * w.x + v.y * w.y + v.z * w.z + v.w * w.w;
  s = warp_sum(s);
  if (lane == 0) out[wv] = s + be2[0];
}

extern "C" void kernel_launch(void* const* d_in, const int* in_sizes, int n_in,
                              void* d_out, int out_size, void* d_ws, size_t ws_size,
                              hipStream_t stream) {
  const float* cell_h  = (const float*)d_in[0];
  const float* pos_emb = (const float*)d_in[1];
  const float* mf_emb  = (const float*)d_in[2];
  const float* W1  = (const float*)d_in[3];
  const float* al1 = (const float*)d_in[4];
  const float* ar1 = (const float*)d_in[5];
  const float* b1  = (const float*)d_in[6];
  const float* W2  = (const float*)d_in[7];
  const float* al2 = (const float*)d_in[8];
  const float* ar2 = (const float*)d_in[9];
  const float* b2  = (const float*)d_in[10];
  const float* Wg1 = (const float*)d_in[11];
  const float* bg1 = (const float*)d_in[12];
  const float* g_gamma = (const float*)d_in[13];
  const float* g_beta  = (const float*)d_in[14];
  const float* g_mean  = (const float*)d_in[15];
  const float* g_var   = (const float*)d_in[16];
  const float* Wg2 = (const float*)d_in[17];
  const float* bg2 = (const float*)d_in[18];
  const float* We1 = (const float*)d_in[19];
  const float* be1 = (const float*)d_in[20];
  const float* e_gamma = (const float*)d_in[21];
  const float* e_beta  = (const float*)d_in[22];
  const float* e_mean  = (const float*)d_in[23];
  const float* e_var   = (const float*)d_in[24];
  const float* We2 = (const float*)d_in[25];
  const float* be2 = (const float*)d_in[26];
  const int* src = (const int*)d_in[27];
  const int* dst = (const int*)d_in[28];
  const int* row_pos = (const int*)d_in[29];
  const int* col_pos = (const int*)d_in[30];
  const int* row_mf  = (const int*)d_in[31];
  const int* col_mf  = (const int*)d_in[32];
  const int* pairs   = (const int*)d_in[33];

  const int N = in_sizes[0] / 768;
  const int E = in_sizes[27];
  const int P = in_sizes[33] / 2;

  float* ws = (float*)d_ws;
  float* featA = ws;                            // [N,512]
  float* h1    = featA + (size_t)N * 512;       // [N,512]
  float* h2    = h1 + (size_t)N * 512;          // [N,512]
  float* el    = h2 + (size_t)N * 512;          // [N,4]
  float* er    = el + (size_t)N * 4;            // [N,4]
  int* offsets = (int*)(er + (size_t)N * 4);    // [N+1]
  int* counts  = offsets + (N + 1);             // [N] (reused as scatter cursor)
  int* csr_src = counts + N;                    // [E]
  float* g_tmp = featA;                         // [N,256] (featA dead by then)
  float* e_tmp = featA + (size_t)N * 256;       // [P,256] (spans dead featA/h1)

  const dim3 blk(16, 16);
  const int mtiles = (N + 63) / 64;
  const int nodeWaves = (N + 3) / 4;

  // ---- CSR build (once; shared by both GAT layers) ----
  hipMemsetAsync(counts, 0, (size_t)N * sizeof(int), stream);
  hist_kernel<<<(E + 255) / 256, 256, 0, stream>>>(dst, counts, E);
  scan_kernel<<<1, 1024, 0, stream>>>(counts, offsets, N);
  hipMemsetAsync(counts, 0, (size_t)N * sizeof(int), stream);  // -> cursor
  scatter_kernel<<<(E + 255) / 256, 256, 0, stream>>>(src, dst, offsets, counts, csr_src, E);

  // ---- embed + GAT layer 1 ----
  gemm_kernel<1, false><<<dim3(8, mtiles), blk, 0, stream>>>(
      nullptr, W1, featA, N, 832, 512,
      cell_h, pos_emb, mf_emb, row_pos, col_pos, row_mf, col_mf,
      nullptr, nullptr, nullptr, nullptr, nullptr, nullptr);
  elr_kernel<<<nodeWaves, 256, 0, stream>>>(featA, al1, ar1, el, er, N);
  gat_aggregate_kernel<false><<<nodeWaves, 256, 0, stream>>>(
      csr_src, offsets, el, er, featA, b1, nullptr, h1, N);

  // ---- GAT layer 2 (identity residual) ----
  gemm_kernel<0, false><<<dim3(8, mtiles), blk, 0, stream>>>(
      h1, W2, featA, N, 512, 512,
      nullptr, nullptr, nullptr, nullptr, nullptr, nullptr, nullptr,
      nullptr, nullptr, nullptr, nullptr, nullptr, nullptr);
  elr_kernel<<<nodeWaves, 256, 0, stream>>>(featA, al2, ar2, el, er, N);
  gat_aggregate_kernel<true><<<nodeWaves, 256, 0, stream>>>(
      csr_src, offsets, el, er, featA, b2, h1, h2, N);

  // ---- comp_and_gid head ----
  gemm_kernel<0, true><<<dim3(4, mtiles), blk, 0, stream>>>(
      h2, Wg1, g_tmp, N, 512, 256,
      nullptr, nullptr, nullptr, nullptr, nullptr, nullptr, nullptr,
      nullptr, bg1, g_gamma, g_beta, g_mean, g_var);
  gid2_kernel<<<nodeWaves, 256, 0, stream>>>(g_tmp, Wg2, bg2, (float*)d_out, N);

  // ---- edge head ----
  gemm_kernel<2, true><<<dim3(4, (P + 63) / 64), blk, 0, stream>>>(
      h2, We1, e_tmp, P, 1024, 256,
      nullptr, nullptr, nullptr, nullptr, nullptr, nullptr, nullptr,
      pairs, be1, e_gamma, e_beta, e_mean, e_var);
  edge2_kernel<<<(P + 3) / 4, 256, 0, stream>>>(
      e_tmp, We2, be2, (float*)d_out + (size_t)N * 4, P);
}

// Round 3
// 811.887 us; speedup vs baseline: 11.4889x; 3.5475x over previous
//
#include <hip/hip_runtime.h>
#include <math.h>

// GNN_2_Model: fused-embed -> GAT1 -> GAT2(+res) -> gid head & edge head.
// Round 2: bf16 MFMA GEMMs (mfma_f32_16x16x32_bf16), bf16 activations.
// ws layout: X0 bf16 [N,832] | featB bf16 [N,512] | h1 bf16 [N,512] | h2 bf16 [N,512]
//   | W1t [512,832] | W2t [512,512] | Wg1t [256,512] | We1t [256,1024] (all bf16)
//   | el,er f32 [N,4] | offsets [N+1] | counts [N] | csr_src [E]
//   g_tmp bf16 [N,256] reuses X0; e_tmp bf16 [P,256] at X0+N*256 (spills into dead featB).

typedef __attribute__((ext_vector_type(8))) short short8;   // 8 x bf16 (4 VGPR)
typedef __attribute__((ext_vector_type(4))) float f32x4;    // MFMA accum
typedef unsigned short ushort;

__device__ __forceinline__ float b2f(ushort h) {
  union { unsigned u; float f; } v; v.u = ((unsigned)h) << 16; return v.f;
}
__device__ __forceinline__ ushort f2b(float f) {
  union { float f; unsigned u; } v; v.f = f;
  unsigned r = v.u + 0x7fffu + ((v.u >> 16) & 1u);  // round-to-nearest-even
  return (ushort)(r >> 16);
}
__device__ __forceinline__ void up4(uint2 q, float* o) {
  o[0] = b2f((ushort)(q.x & 0xffffu)); o[1] = b2f((ushort)(q.x >> 16));
  o[2] = b2f((ushort)(q.y & 0xffffu)); o[3] = b2f((ushort)(q.y >> 16));
}
__device__ __forceinline__ uint2 pk4(const float* o) {
  uint2 q;
  q.x = (unsigned)f2b(o[0]) | ((unsigned)f2b(o[1]) << 16);
  q.y = (unsigned)f2b(o[2]) | ((unsigned)f2b(o[3]) << 16);
  return q;
}
__device__ __forceinline__ float warp_sum(float v) {
#pragma unroll
  for (int o = 32; o > 0; o >>= 1) v += __shfl_xor(v, o);
  return v;
}

// ---------------- fused embedding -> X0 bf16 [N,832] ----------------
__global__ __launch_bounds__(256) void embed_kernel(
    const float* __restrict__ cell_h, const float* __restrict__ pos_emb,
    const float* __restrict__ mf_emb,
    const int* __restrict__ row_pos, const int* __restrict__ col_pos,
    const int* __restrict__ row_mf, const int* __restrict__ col_mf,
    ushort* __restrict__ X0, int N)
{
  const int idx = blockIdx.x * 256 + threadIdx.x;
  const int total = N * 104;  // 832/8 chunks per node
  if (idx >= total) return;
  const int n = idx / 104;
  const int c8 = (idx - n * 104) * 8;
  float o[8];
  if (c8 < 768) {
    const int rp = row_pos[n], cp = col_pos[n];
    const float4* pc = (const float4*)(cell_h + (size_t)n * 768 + c8);
    const float4* pr = (const float4*)(pos_emb + (size_t)rp * 768 + c8);
    const float4* pq = (const float4*)(pos_emb + (size_t)cp * 768 + c8);
    float4 c0 = pc[0], c1 = pc[1], r0 = pr[0], r1 = pr[1], q0 = pq[0], q1 = pq[1];
    o[0] = c0.x + r0.x + q0.x; o[1] = c0.y + r0.y + q0.y;
    o[2] = c0.z + r0.z + q0.z; o[3] = c0.w + r0.w + q0.w;
    o[4] = c1.x + r1.x + q1.x; o[5] = c1.y + r1.y + q1.y;
    o[6] = c1.z + r1.z + q1.z; o[7] = c1.w + r1.w + q1.w;
  } else {
    const int rm = min(row_mf[n], 5), cm = min(col_mf[n], 5);
    const int j0 = c8 - 768;
    const float4* pr = (const float4*)(mf_emb + (size_t)rm * 64 + j0);
    const float4* pq = (const float4*)(mf_emb + (size_t)cm * 64 + j0);
    float4 r0 = pr[0], r1 = pr[1], q0 = pq[0], q1 = pq[1];
    o[0] = r0.x + q0.x; o[1] = r0.y + q0.y; o[2] = r0.z + q0.z; o[3] = r0.w + q0.w;
    o[4] = r1.x + q1.x; o[5] = r1.y + q1.y; o[6] = r1.z + q1.z; o[7] = r1.w + q1.w;
  }
  uint4 pk;
  pk.x = (unsigned)f2b(o[0]) | ((unsigned)f2b(o[1]) << 16);
  pk.y = (unsigned)f2b(o[2]) | ((unsigned)f2b(o[3]) << 16);
  pk.z = (unsigned)f2b(o[4]) | ((unsigned)f2b(o[5]) << 16);
  pk.w = (unsigned)f2b(o[6]) | ((unsigned)f2b(o[7]) << 16);
  *(uint4*)(X0 + (size_t)n * 832 + c8) = pk;
}

// ---------------- weight transpose+convert: Wt[n][k] = bf16(W[k][n]) ----------------
__global__ __launch_bounds__(256) void wtrans_kernel(
    const float* __restrict__ W, ushort* __restrict__ Wt, int K, int N)
{
  const int idx = blockIdx.x * 256 + threadIdx.x;
  if (idx >= K * N) return;
  const int n = idx / K, k = idx - n * K;
  Wt[idx] = f2b(W[(size_t)k * N + n]);
}

// ---------------- bf16 MFMA GEMM: C[M,Ncols] = A[M,K] @ Bt[Ncols,K]^T ----------------
// 128x128 tile, BK=64, 256 thr = 4 waves (2x2 of 64x64), mfma_f32_16x16x32_bf16.
// LDS is fragment-major: subtile(mb,ks) holds 512 bf16 at lane*8+j, so frag loads are
// contiguous ds_read_b128 (conflict-free). Staging splits each 16B chunk into two
// ds_write_b64 granules per the k-group frag mapping (k-permutation-consistent for A&B).
// MODE 0: A row r = A[r] (bf16, stride K). MODE 2: A row r = concat(A[pairs[2r]], A[pairs[2r+1]]), K=1024.
// BNRELU: y = relu(x*sa + sb), sa/sb folded from bias/BN params.
template <int MODE, bool BNRELU>
__global__ __launch_bounds__(256) void mfma_gemm_kernel(
    const ushort* __restrict__ A, const ushort* __restrict__ Bt,
    ushort* __restrict__ C, int M, int K, int Ncols,
    const int* __restrict__ pairs,
    const float* __restrict__ bias, const float* __restrict__ gamma,
    const float* __restrict__ beta, const float* __restrict__ mean,
    const float* __restrict__ var)
{
  __shared__ ushort As[8192];  // 128 x 64 bf16, fragment-major
  __shared__ ushort Bs[8192];  // 128 x 64 bf16, fragment-major
  const int tid = threadIdx.x;
  const int lane = tid & 63;
  const int wave = tid >> 6;
  const int wm = wave >> 1, wn = wave & 1;
  const int m0 = blockIdx.y * 128, n0 = blockIdx.x * 128;

  f32x4 acc[4][4];
#pragma unroll
  for (int i = 0; i < 4; ++i)
#pragma unroll
    for (int j = 0; j < 4; ++j) acc[i][j] = (f32x4){0.f, 0.f, 0.f, 0.f};

  for (int k0 = 0; k0 < K; k0 += 64) {
    uint4 aval[4], bval[4];
#pragma unroll
    for (int cc = 0; cc < 4; ++cc) {
      const int c = tid + cc * 256;          // chunk id 0..1023
      const int r = c >> 3, kc = c & 7;      // tile row, 16B chunk within BK
      const int k = k0 + kc * 8;
      const ushort* ap;
      if (MODE == 0) {
        const int gr = m0 + r;
        ap = (gr < M) ? (A + (size_t)gr * K + k) : A;  // OOB rows: garbage ok (not stored)
      } else {
        const int gr = m0 + r;
        int node = 0;
        if (gr < M) node = pairs[2 * gr + (k >= 512)];
        ap = A + (size_t)node * 512 + (k & 511);
      }
      aval[cc] = *(const uint4*)ap;
      bval[cc] = *(const uint4*)(Bt + (size_t)(n0 + r) * K + k);
    }
    __syncthreads();  // previous tile's frags consumed
#pragma unroll
    for (int cc = 0; cc < 4; ++cc) {
      const int c = tid + cc * 256;
      const int r = c >> 3, kc = c & 7;
      const int mb = r >> 4, mm = r & 15;
      const int ks = kc >> 2;
      const int g0 = (kc & 1) * 2;            // k-group of first granule
      const int j0 = ((kc >> 1) & 1) * 4;     // reg offset (which K=16 half)
      const int sub = (mb * 2 + ks) << 9;     // 512 shorts per subtile
      uint2 w;
      w.x = aval[cc].x; w.y = aval[cc].y;
      *(uint2*)(As + sub + ((mm + 16 * g0) << 3) + j0) = w;
      w.x = aval[cc].z; w.y = aval[cc].w;
      *(uint2*)(As + sub + ((mm + 16 * (g0 + 1)) << 3) + j0) = w;
      w.x = bval[cc].x; w.y = bval[cc].y;
      *(uint2*)(Bs + sub + ((mm + 16 * g0) << 3) + j0) = w;
      w.x = bval[cc].z; w.y = bval[cc].w;
      *(uint2*)(Bs + sub + ((mm + 16 * (g0 + 1)) << 3) + j0) = w;
    }
    __syncthreads();

    short8 af[4][2], bfr[4][2];
#pragma unroll
    for (int f = 0; f < 4; ++f)
#pragma unroll
      for (int ks = 0; ks < 2; ++ks) {
        af[f][ks]  = *(const short8*)(As + ((((wm * 4 + f) * 2) + ks) << 9) + (lane << 3));
        bfr[f][ks] = *(const short8*)(Bs + ((((wn * 4 + f) * 2) + ks) << 9) + (lane << 3));
      }
#pragma unroll
    for (int mf = 0; mf < 4; ++mf)
#pragma unroll
      for (int nf = 0; nf < 4; ++nf)
#pragma unroll
        for (int ks = 0; ks < 2; ++ks)
          acc[mf][nf] = __builtin_amdgcn_mfma_f32_16x16x32_bf16(
              af[mf][ks], bfr[nf][ks], acc[mf][nf], 0, 0, 0);
  }

  // epilogue: C layout col = lane&15, row = (lane>>4)*4 + j  [measured m89]
#pragma unroll
  for (int nf = 0; nf < 4; ++nf) {
    const int col = n0 + (wn * 4 + nf) * 16 + (lane & 15);
    float sa = 1.f, sb = 0.f;
    if (BNRELU) {
      const float rs = rsqrtf(var[col] + 1e-5f);
      sa = rs * gamma[col];
      sb = beta[col] + (bias[col] - mean[col]) * sa;
    }
#pragma unroll
    for (int mf = 0; mf < 4; ++mf) {
      const int rbase = m0 + (wm * 4 + mf) * 16 + (lane >> 4) * 4;
#pragma unroll
      for (int j = 0; j < 4; ++j) {
        const int row = rbase + j;
        if (row >= M) continue;
        float v = acc[mf][nf][j];
        if (BNRELU) v = fmaxf(fmaf(v, sa, sb), 0.f);
        C[(size_t)row * Ncols + col] = f2b(v);
      }
    }
  }
}

// el[n,h] = sum_d feat[n,h,d]*al[h,d]; er likewise. One wave per node. feat bf16.
__global__ __launch_bounds__(256) void elr_kernel(
    const ushort* __restrict__ feat, const float* __restrict__ al,
    const float* __restrict__ ar, float* __restrict__ el, float* __restrict__ er, int N)
{
  const int wv = (blockIdx.x * 256 + threadIdx.x) >> 6;
  const int lane = threadIdx.x & 63;
  if (wv >= N) return;
  const ushort* f = feat + (size_t)wv * 512;
#pragma unroll
  for (int h = 0; h < 4; h++) {
    const float x0 = b2f(f[h * 128 + lane]);
    const float x1 = b2f(f[h * 128 + 64 + lane]);
    float sl = x0 * al[h * 128 + lane] + x1 * al[h * 128 + 64 + lane];
    float sr = x0 * ar[h * 128 + lane] + x1 * ar[h * 128 + 64 + lane];
    sl = warp_sum(sl);
    sr = warp_sum(sr);
    if (lane == 0) { el[(size_t)wv * 4 + h] = sl; er[(size_t)wv * 4 + h] = sr; }
  }
}

// ---------------- CSR build (by dst), done once ----------------
__global__ __launch_bounds__(256) void hist_kernel(
    const int* __restrict__ dst, int* __restrict__ counts, int E)
{
  const int e = blockIdx.x * 256 + threadIdx.x;
  if (e < E) atomicAdd(counts + dst[e], 1);
}

__global__ __launch_bounds__(1024) void scan_kernel(
    const int* __restrict__ counts, int* __restrict__ offsets, int N)
{
  __shared__ int sums[1024];
  const int t = threadIdx.x;
  const int chunk = (N + 1023) >> 10;
  const int beg = t * chunk;
  const int end = min(beg + chunk, N);
  int s = 0;
  for (int i = beg; i < end; ++i) s += counts[i];
  sums[t] = s;
  __syncthreads();
  for (int o = 1; o < 1024; o <<= 1) {
    int u = (t >= o) ? sums[t - o] : 0;
    __syncthreads();
    sums[t] += u;
    __syncthreads();
  }
  int run = sums[t] - s;
  for (int i = beg; i < end; ++i) { offsets[i] = run; run += counts[i]; }
  if (t == 1023) offsets[N] = sums[1023];
}

__global__ __launch_bounds__(256) void scatter_kernel(
    const int* __restrict__ src, const int* __restrict__ dst,
    const int* __restrict__ offsets, int* __restrict__ cursor,
    int* __restrict__ csr_src, int E)
{
  const int e = blockIdx.x * 256 + threadIdx.x;
  if (e >= E) return;
  const int d = dst[e];
  const int pos = offsets[d] + atomicAdd(cursor + d, 1);
  csr_src[pos] = src[e];
}

// ---------------- GAT aggregate: one wave per dst node (bf16 feat/resid/out) --------
template <bool RES>
__global__ __launch_bounds__(256) void gat_aggregate_kernel(
    const int* __restrict__ csr_src, const int* __restrict__ offsets,
    const float* __restrict__ el, const float* __restrict__ er,
    const ushort* __restrict__ feat, const float* __restrict__ bias,
    const ushort* __restrict__ resid, ushort* __restrict__ out, int N)
{
  const int node = (blockIdx.x * 256 + threadIdx.x) >> 6;
  const int lane = threadIdx.x & 63;
  if (node >= N) return;
  const int beg = offsets[node], end = offsets[node + 1];
  const float4 erd = *(const float4*)(er + (size_t)node * 4);

  // pass 1: softmax denominators
  float d0 = 0.f, d1 = 0.f, d2 = 0.f, d3 = 0.f;
  for (int i = beg + lane; i < end; i += 64) {
    const int s = csr_src[i];
    const float4 l = *(const float4*)(el + (size_t)s * 4);
    float x0 = l.x + erd.x, x1 = l.y + erd.y, x2 = l.z + erd.z, x3 = l.w + erd.w;
    x0 = x0 > 0.f ? x0 : 0.2f * x0;
    x1 = x1 > 0.f ? x1 : 0.2f * x1;
    x2 = x2 > 0.f ? x2 : 0.2f * x2;
    x3 = x3 > 0.f ? x3 : 0.2f * x3;
    d0 += __expf(x0); d1 += __expf(x1); d2 += __expf(x2); d3 += __expf(x3);
  }
  d0 = warp_sum(d0); d1 = warp_sum(d1); d2 = warp_sum(d2); d3 = warp_sum(d3);
  const float r0 = 1.f / d0, r1 = 1.f / d1, r2 = 1.f / d2, r3 = 1.f / d3;

  // pass 2: weighted gather-accumulate. lane owns feats [lane*4,+4) and [256+lane*4,+4)
  float a0[4] = {0.f, 0.f, 0.f, 0.f};
  float a1[4] = {0.f, 0.f, 0.f, 0.f};
  for (int i = beg; i < end; ++i) {
    const int s = csr_src[i];  // uniform across wave
    const float4 l = *(const float4*)(el + (size_t)s * 4);
    float x0 = l.x + erd.x, x1 = l.y + erd.y, x2 = l.z + erd.z, x3 = l.w + erd.w;
    x0 = x0 > 0.f ? x0 : 0.2f * x0;
    x1 = x1 > 0.f ? x1 : 0.2f * x1;
    x2 = x2 > 0.f ? x2 : 0.2f * x2;
    x3 = x3 > 0.f ? x3 : 0.2f * x3;
    const float al0 = __expf(x0) * r0, al1 = __expf(x1) * r1;
    const float al2 = __expf(x2) * r2, al3 = __expf(x3) * r3;
    const float aa = (lane < 32) ? al0 : al1;
    const float ab = (lane < 32) ? al2 : al3;
    const ushort* f = feat + (size_t)s * 512;
    float v0[4], v1[4];
    up4(*(const uint2*)(f + lane * 4), v0);
    up4(*(const uint2*)(f + 256 + lane * 4), v1);
#pragma unroll
    for (int j = 0; j < 4; ++j) {
      a0[j] = fmaf(v0[j], aa, a0[j]);
      a1[j] = fmaf(v1[j], ab, a1[j]);
    }
  }

  const float4 b0 = *(const float4*)(bias + lane * 4);
  const float4 b1 = *(const float4*)(bias + 256 + lane * 4);
  a0[0] += b0.x; a0[1] += b0.y; a0[2] += b0.z; a0[3] += b0.w;
  a1[0] += b1.x; a1[1] += b1.y; a1[2] += b1.z; a1[3] += b1.w;
  if (RES) {
    const ushort* rr = resid + (size_t)node * 512;
    float q0[4], q1[4];
    up4(*(const uint2*)(rr + lane * 4), q0);
    up4(*(const uint2*)(rr + 256 + lane * 4), q1);
#pragma unroll
    for (int j = 0; j < 4; ++j) { a0[j] += q0[j]; a1[j] += q1[j]; }
  }
  ushort* op = out + (size_t)node * 512;
  *(uint2*)(op + lane * 4) = pk4(a0);
  *(uint2*)(op + 256 + lane * 4) = pk4(a1);
}

// gid logits: one wave per node; g bf16 [N,256] @ Wg2[256,4] + bg2.
__global__ __launch_bounds__(256) void gid2_kernel(
    const ushort* __restrict__ g, const float* __restrict__ Wg2,
    const float* __restrict__ bg2, float* __restrict__ out, int N)
{
  const int wv = (blockIdx.x * 256 + threadIdx.x) >> 6;
  const int lane = threadIdx.x & 63;
  if (wv >= N) return;
  float ga[4];
  up4(*(const uint2*)(g + (size_t)wv * 256 + lane * 4), ga);
  float a0 = 0.f, a1 = 0.f, a2 = 0.f, a3 = 0.f;
  const float* wp = Wg2 + (size_t)lane * 16;
#pragma unroll
  for (int j = 0; j < 4; j++) {
    const float4 w = *(const float4*)(wp + j * 4);
    a0 += ga[j] * w.x; a1 += ga[j] * w.y; a2 += ga[j] * w.z; a3 += ga[j] * w.w;
  }
  a0 = warp_sum(a0); a1 = warp_sum(a1); a2 = warp_sum(a2); a3 = warp_sum(a3);
  if (lane == 0) {
    float4 o = {a0 + bg2[0], a1 + bg2[1], a2 + bg2[2], a3 + bg2[3]};
    *(float4*)(out + (size_t)wv * 4) = o;
  }
}

// edge logits: one wave per pair; e bf16 [P,256] @ We2[256,1] + be2.
__global__ __launch_bounds__(256) void edge2_kernel(
    const ushort* __restrict__ etmp, const float* __restrict__ We2,
    const float* __restrict__ be2, float* __restrict__ out, int P)
{
  const int wv = (blockIdx.x * 256 + threadIdx.x) >> 6;
  const int lane = threadIdx.x & 63;
  if (wv >= P) return;
  float v[4];
  up4(*(const uint2*)(etmp + (size_t)wv * 256 + lane * 4), v);
  const float4 w = *(const float4*)(We2 + (size_t)lane * 4);
  float s = v[0] * w.x + v[1] * w.y + v[2] * w.z + v[3] * w.w;
  s = warp_sum(s);
  if (lane == 0) out[wv] = s + be2[0];
}

extern "C" void kernel_launch(void* const* d_in, const int* in_sizes, int n_in,
                              void* d_out, int out_size, void* d_ws, size_t ws_size,
                              hipStream_t stream) {
  const float* cell_h  = (const float*)d_in[0];
  const float* pos_emb = (const float*)d_in[1];
  const float* mf_emb  = (const float*)d_in[2];
  const float* W1  = (const float*)d_in[3];
  const float* al1 = (const float*)d_in[4];
  const float* ar1 = (const float*)d_in[5];
  const float* b1  = (const float*)d_in[6];
  const float* W2  = (const float*)d_in[7];
  const float* al2 = (const float*)d_in[8];
  const float* ar2 = (const float*)d_in[9];
  const float* b2  = (const float*)d_in[10];
  const float* Wg1 = (const float*)d_in[11];
  const float* bg1 = (const float*)d_in[12];
  const float* g_gamma = (const float*)d_in[13];
  const float* g_beta  = (const float*)d_in[14];
  const float* g_mean  = (const float*)d_in[15];
  const float* g_var   = (const float*)d_in[16];
  const float* Wg2 = (const float*)d_in[17];
  const float* bg2 = (const float*)d_in[18];
  const float* We1 = (const float*)d_in[19];
  const float* be1 = (const float*)d_in[20];
  const float* e_gamma = (const float*)d_in[21];
  const float* e_beta  = (const float*)d_in[22];
  const float* e_mean  = (const float*)d_in[23];
  const float* e_var   = (const float*)d_in[24];
  const float* We2 = (const float*)d_in[25];
  const float* be2 = (const float*)d_in[26];
  const int* src = (const int*)d_in[27];
  const int* dst = (const int*)d_in[28];
  const int* row_pos = (const int*)d_in[29];
  const int* col_pos = (const int*)d_in[30];
  const int* row_mf  = (const int*)d_in[31];
  const int* col_mf  = (const int*)d_in[32];
  const int* pairs   = (const int*)d_in[33];

  const int N = in_sizes[0] / 768;
  const int E = in_sizes[27];
  const int P = in_sizes[33] / 2;

  ushort* X0    = (ushort*)d_ws;                 // [N,832]
  ushort* featB = X0 + (size_t)N * 832;          // [N,512]
  ushort* h1    = featB + (size_t)N * 512;       // [N,512]
  ushort* h2    = h1 + (size_t)N * 512;          // [N,512]
  ushort* W1t   = h2 + (size_t)N * 512;          // [512,832]
  ushort* W2t   = W1t + 512 * 832;               // [512,512]
  ushort* Wg1t  = W2t + 512 * 512;               // [256,512]
  ushort* We1t  = Wg1t + 256 * 512;              // [256,1024]
  float* el     = (float*)(We1t + 256 * 1024);   // [N,4]
  float* er     = el + (size_t)N * 4;            // [N,4]
  int* offsets  = (int*)(er + (size_t)N * 4);    // [N+1]
  int* counts   = offsets + (N + 1);             // [N]
  int* csr_src  = counts + N;                    // [E]
  ushort* g_tmp = X0;                            // [N,256] (X0 dead after GEMM1)
  ushort* e_tmp = X0 + (size_t)N * 256;          // [P,256] (spans dead X0/featB)

  const int nodeWaves = (N + 3) / 4;
  const int mtiles = (N + 127) / 128;

  // ---- CSR build (once) ----
  hipMemsetAsync(counts, 0, (size_t)N * sizeof(int), stream);
  hist_kernel<<<(E + 255) / 256, 256, 0, stream>>>(dst, counts, E);
  scan_kernel<<<1, 1024, 0, stream>>>(counts, offsets, N);
  hipMemsetAsync(counts, 0, (size_t)N * sizeof(int), stream);
  scatter_kernel<<<(E + 255) / 256, 256, 0, stream>>>(src, dst, offsets, counts, csr_src, E);

  // ---- weights -> bf16 transposed ----
  wtrans_kernel<<<(832 * 512 + 255) / 256, 256, 0, stream>>>(W1, W1t, 832, 512);
  wtrans_kernel<<<(512 * 512 + 255) / 256, 256, 0, stream>>>(W2, W2t, 512, 512);
  wtrans_kernel<<<(512 * 256 + 255) / 256, 256, 0, stream>>>(Wg1, Wg1t, 512, 256);
  wtrans_kernel<<<(1024 * 256 + 255) / 256, 256, 0, stream>>>(We1, We1t, 1024, 256);

  // ---- fused embedding -> X0 bf16 ----
  embed_kernel<<<(N * 104 + 255) / 256, 256, 0, stream>>>(
      cell_h, pos_emb, mf_emb, row_pos, col_pos, row_mf, col_mf, X0, N);

  // ---- GAT layer 1 ----
  mfma_gemm_kernel<0, false><<<dim3(4, mtiles), 256, 0, stream>>>(
      X0, W1t, featB, N, 832, 512, nullptr, nullptr, nullptr, nullptr, nullptr, nullptr);
  elr_kernel<<<nodeWaves, 256, 0, stream>>>(featB, al1, ar1, el, er, N);
  gat_aggregate_kernel<false><<<nodeWaves, 256, 0, stream>>>(
      csr_src, offsets, el, er, featB, b1, nullptr, h1, N);

  // ---- GAT layer 2 (identity residual) ----
  mfma_gemm_kernel<0, false><<<dim3(4, mtiles), 256, 0, stream>>>(
      h1, W2t, featB, N, 512, 512, nullptr, nullptr, nullptr, nullptr, nullptr, nullptr);
  elr_kernel<<<nodeWaves, 256, 0, stream>>>(featB, al2, ar2, el, er, N);
  gat_aggregate_kernel<true><<<nodeWaves, 256, 0, stream>>>(
      csr_src, offsets, el, er, featB, b2, h1, h2, N);

  // ---- comp_and_gid head ----
  mfma_gemm_kernel<0, true><<<dim3(2, mtiles), 256, 0, stream>>>(
      h2, Wg1t, g_tmp, N, 512, 256, nullptr, bg1, g_gamma, g_beta, g_mean, g_var);
  gid2_kernel<<<nodeWaves, 256, 0, stream>>>(g_tmp, Wg2, bg2, (float*)d_out, N);

  // ---- edge head ----
  mfma_gemm_kernel<2, true><<<dim3(2, (P + 127) / 128), 256, 0, stream>>>(
      h2, We1t, e_tmp, P, 1024, 256, pairs, be1, e_gamma, e_beta, e_mean, e_var);
  edge2_kernel<<<(P + 3) / 4, 256, 0, stream>>>(
      e_tmp, We2, be2, (float*)d_out + (size_t)N * 4, P);
}